// Round 7
// baseline (400.737 us; speedup 1.0000x reference)
//
#include <hip/hip_runtime.h>
#include <hip/hip_bf16.h>
#include <stdint.h>

// ---- problem constants ----
#define TOKENS 4096      // B*N = 2*2048
#define SEQ    2048
#define CMODEL 1024
#define HEADS  16
#define HDIM   64
#define DFF    4096
#define NT     (SEQ / 64)

typedef __attribute__((ext_vector_type(8))) short     short8;
typedef __attribute__((ext_vector_type(8))) unsigned short ushort8;
typedef __attribute__((ext_vector_type(4))) unsigned short ushort4v;
typedef __attribute__((ext_vector_type(4))) float     f32x4;

typedef const __attribute__((address_space(1))) void gbl_cvoid;
typedef __attribute__((address_space(3))) void lds_void;

__device__ inline unsigned short f2bf(float f) {
  unsigned int u = __builtin_bit_cast(unsigned int, f);
  u += 0x7fffu + ((u >> 16) & 1u);
  return (unsigned short)(u >> 16);
}
__device__ inline float bf2f(unsigned short h) {
  unsigned int u = ((unsigned int)h) << 16;
  return __builtin_bit_cast(float, u);
}

__device__ inline void gload_lds16(const unsigned short* g, unsigned short* lds) {
  __builtin_amdgcn_global_load_lds((gbl_cvoid*)g, (lds_void*)lds, 16, 0, 0);
}

// ---------------- fused f32 -> bf16 convert for all 5 tensors ----------------
#define CVT_B0 524288    // src      4096*1024/8
#define CVT_B1 917504    // + w_qkv  3*1024*1024/8
#define CVT_B2 1048576   // + w_proj 1024*1024/8
#define CVT_B3 1572864   // + w1     4096*1024/8
#define CVT_B4 2097152   // + w2     1024*4096/8
__global__ __launch_bounds__(256) void k_cvt_all(
    const float* __restrict__ src, const float* __restrict__ wqkv,
    const float* __restrict__ wproj, const float* __restrict__ w1,
    const float* __restrict__ w2,
    unsigned short* __restrict__ o_src, unsigned short* __restrict__ o_wqkv,
    unsigned short* __restrict__ o_wproj, unsigned short* __restrict__ o_w1,
    unsigned short* __restrict__ o_w2)
{
  const int i = blockIdx.x * 256 + threadIdx.x;
  const float* in;
  unsigned short* out;
  int off;
  if (i < CVT_B0)      { in = src;   out = o_src;   off = i; }
  else if (i < CVT_B1) { in = wqkv;  out = o_wqkv;  off = i - CVT_B0; }
  else if (i < CVT_B2) { in = wproj; out = o_wproj; off = i - CVT_B1; }
  else if (i < CVT_B3) { in = w1;    out = o_w1;    off = i - CVT_B2; }
  else                 { in = w2;    out = o_w2;    off = i - CVT_B3; }
  const float4* p = (const float4*)in + 2 * (size_t)off;
  float4 a = p[0], b = p[1];
  ushort8 o;
  o[0] = f2bf(a.x); o[1] = f2bf(a.y); o[2] = f2bf(a.z); o[3] = f2bf(a.w);
  o[4] = f2bf(b.x); o[5] = f2bf(b.y); o[6] = f2bf(b.z); o[7] = f2bf(b.w);
  ((ushort8*)out)[off] = o;
}

// ---------------- bf16 BT-GEMM 128x128: C[M,N] = A[M,K] @ B[N,K]^T --------
// BK=32, 4 waves (2x2). 3-deep LDS pipeline: stage(kt+2), counted vmcnt(8).
// EPI: 0 = bf16 plain; 2 = bf16 relu(+bias); 4 = f32 partial (split-K via blockIdx.z)
template<int EPI>
__global__ __launch_bounds__(256) void k_gemm_bt(
    const unsigned short* __restrict__ A,
    const unsigned short* __restrict__ B,
    unsigned short* __restrict__ Cb,
    float* __restrict__ Cf,
    const float* __restrict__ bias,
    int M, int N, int K, int kspan)
{
  __shared__ unsigned short As[3][128 * 32];
  __shared__ unsigned short Bs[3][128 * 32];
  const int t = threadIdx.x;
  const int lane = t & 63;
  const int w = t >> 6;
  const int wr = w >> 1, wc = w & 1;
  const int nwg = gridDim.x * gridDim.y;
  const int bid = blockIdx.y * gridDim.x + blockIdx.x;
  const int swz = (bid & 7) * (nwg >> 3) + (bid >> 3);
  const int n0 = (swz % gridDim.x) * 128;
  const int m0 = (swz / gridDim.x) * 128;
  const int kbase = blockIdx.z * kspan;

  const int e0 = w * 1024 + lane * 8;
  const int e1 = e0 + 512;
  const int r0 = e0 >> 5, c0 = e0 & 31;
  const int r1 = e1 >> 5, c1 = e1 & 31;

  f32x4 acc[4][4] = {};
  const int lr = lane & 15, lh = lane >> 4;
  const int nkt = kspan >> 5;

  auto stage = [&](int kt, int buf) {
    const int kb = kbase + (kt << 5);
    gload_lds16(A + (size_t)(m0 + r0) * K + kb + c0, &As[buf][w * 1024]);
    gload_lds16(A + (size_t)(m0 + r1) * K + kb + c1, &As[buf][w * 1024 + 512]);
    gload_lds16(B + (size_t)(n0 + r0) * K + kb + c0, &Bs[buf][w * 1024]);
    gload_lds16(B + (size_t)(n0 + r1) * K + kb + c1, &Bs[buf][w * 1024 + 512]);
  };
  stage(0, 0);
  if (nkt > 1) stage(1, 1);

  int buf = 0;
  for (int kt = 0; kt < nkt; ++kt) {
    if (kt + 2 < nkt) {
      const int nb = buf + 2 >= 3 ? buf - 1 : buf + 2;
      stage(kt + 2, nb);
      asm volatile("s_waitcnt vmcnt(8)" ::: "memory");
    } else if (kt + 1 < nkt) {
      asm volatile("s_waitcnt vmcnt(4)" ::: "memory");
    } else {
      asm volatile("s_waitcnt vmcnt(0)" ::: "memory");
    }
    __builtin_amdgcn_s_barrier();
    __builtin_amdgcn_sched_barrier(0);
    short8 af[4], bg[4];
#pragma unroll
    for (int m = 0; m < 4; ++m)
      af[m] = *(const short8*)&As[buf][(wr * 64 + m * 16 + lr) * 32 + lh * 8];
#pragma unroll
    for (int n = 0; n < 4; ++n)
      bg[n] = *(const short8*)&Bs[buf][(wc * 64 + n * 16 + lr) * 32 + lh * 8];
#pragma unroll
    for (int m = 0; m < 4; ++m)
#pragma unroll
      for (int n = 0; n < 4; ++n)
        acc[m][n] = __builtin_amdgcn_mfma_f32_16x16x32_bf16(af[m], bg[n], acc[m][n], 0, 0, 0);
    __builtin_amdgcn_s_barrier();
    __builtin_amdgcn_sched_barrier(0);
    buf = buf + 1 >= 3 ? 0 : buf + 1;
  }

  float* Cfp = (EPI == 4) ? Cf + (size_t)blockIdx.z * ((size_t)M * N) : Cf;
  for (int m = 0; m < 4; ++m) {
    for (int n = 0; n < 4; ++n) {
      const int col = n0 + wc * 64 + n * 16 + lr;
      for (int r = 0; r < 4; ++r) {
        const int row = m0 + wr * 64 + m * 16 + lh * 4 + r;
        const size_t idx = (size_t)row * N + col;
        float v = acc[m][n][r];
        if (EPI == 0) {
          Cb[idx] = f2bf(v);
        } else if (EPI == 2) {
          v += bias[col];
          Cb[idx] = f2bf(v > 0.f ? v : 0.f);
        } else {  // EPI == 4: f32 partial
          Cfp[idx] = v;
        }
      }
    }
  }
}

// ---------------- flash attention: QBLK=64, KVBLK=64, 4 waves ----------------
// Q/K from qk[token][2048]; V pre-transposed vT[h*64+d][token] -> both K and V
// tiles staged via global_load_lds (pre-swizzled source, XOR-swizzled reads).
// One vmcnt(4)+barrier before compute; end-of-iter barrier gives WAR protection.
__global__ __launch_bounds__(256) void k_attn(
    const unsigned short* __restrict__ qk,   // [token][2048]
    const unsigned short* __restrict__ vT,   // [1024][TOKENS]
    unsigned short* __restrict__ outb)       // [token][1024]
{
  __shared__ unsigned short Qs[64 * 64];
  __shared__ unsigned short Ks[2][64 * 64];
  __shared__ unsigned short Vt[2][64 * 64];   // Vt[d][kv], swizzled
  __shared__ unsigned short Ps[4][16 * 72];

  const int t = threadIdx.x, lane = t & 63, w = t >> 6;
  const int bid0 = blockIdx.y * 32 + blockIdx.x;
  const int swz = (bid0 & 7) * 128 + (bid0 >> 3);
  const int bh = swz >> 5;
  const int b = bh >> 4, h = bh & 15;
  const int q0 = (swz & 31) * 64;
  const size_t tokbase = (size_t)b * SEQ;
  const int qoff = h * 64, koff = 1024 + h * 64;
  const size_t vbase = (size_t)(h * 64) * TOKENS + tokbase;
  const int lr = lane & 15, lh = lane >> 4, lh4 = lh * 4;

  // pre-swizzled staging source (rule #21): lane covers (row = base + lane>>3,
  // 16B-slot = (lane&7) ^ (lane>>3)); LDS dest linear.
  const int srow = lane >> 3;
  const int scol = (((lane & 7) ^ srow) & 7) << 3;

  // prologue: Q, K0, V0
  gload_lds16(qk + (tokbase + q0 + w * 16 + srow) * 2048 + qoff + scol, &Qs[w * 1024]);
  gload_lds16(qk + (tokbase + q0 + w * 16 + 8 + srow) * 2048 + qoff + scol, &Qs[w * 1024 + 512]);
  gload_lds16(qk + (tokbase + w * 16 + srow) * 2048 + koff + scol, &Ks[0][w * 1024]);
  gload_lds16(qk + (tokbase + w * 16 + 8 + srow) * 2048 + koff + scol, &Ks[0][w * 1024 + 512]);
  gload_lds16(vT + vbase + (size_t)(w * 16 + srow) * TOKENS + scol, &Vt[0][w * 1024]);
  gload_lds16(vT + vbase + (size_t)(w * 16 + 8 + srow) * TOKENS + scol, &Vt[0][w * 1024 + 512]);
  asm volatile("s_waitcnt vmcnt(0)" ::: "memory");
  __builtin_amdgcn_s_barrier();
  __builtin_amdgcn_sched_barrier(0);

  // Q fragments (B-operand of swapped QK^T), hoisted
  const int qrow = w * 16 + lr;
  const short8 aq0 = *(const short8*)&Qs[qrow * 64 + (((lh ^ (lr & 7)) & 7) << 3)];
  const short8 aq1 = *(const short8*)&Qs[qrow * 64 + ((((lh + 4) ^ (lr & 7)) & 7) << 3)];

  int koffs0[4], koffs1[4], voffs0[4], voffs1[4];
  for (int nf = 0; nf < 4; ++nf) {
    const int krow = nf * 16 + lr;
    koffs0[nf] = krow * 64 + (((lh ^ (lr & 7)) & 7) << 3);
    koffs1[nf] = krow * 64 + ((((lh + 4) ^ (lr & 7)) & 7) << 3);
    voffs0[nf] = koffs0[nf];   // Vt[d][kv] same row/slot structure (d&7 == lr&7)
    voffs1[nf] = koffs1[nf];
  }
  const unsigned short* pa0p = &Ps[w][lr * 72 + lh * 8];
  const unsigned short* pa1p = &Ps[w][lr * 72 + 32 + lh * 8];

  float m_run = -1e30f, l_run = 0.f;
  f32x4 oacc[4] = {};
  const float SCL = 0.125f * 1.44269504089f;  // head_scale * log2(e)

#define ATTN_STEP(CUR, KT)                                                        \
  {                                                                               \
    const int ktn = (KT) + 1;                                                     \
    if (ktn < NT) {                                                               \
      gload_lds16(qk + (tokbase + ktn * 64 + w * 16 + srow) * 2048 + koff + scol, \
                  &Ks[1 - (CUR)][w * 1024]);                                      \
      gload_lds16(qk + (tokbase + ktn * 64 + w * 16 + 8 + srow) * 2048 + koff + scol,\
                  &Ks[1 - (CUR)][w * 1024 + 512]);                                \
      gload_lds16(vT + vbase + ktn * 64 + (size_t)(w * 16 + srow) * TOKENS + scol,\
                  &Vt[1 - (CUR)][w * 1024]);                                      \
      gload_lds16(vT + vbase + ktn * 64 + (size_t)(w * 16 + 8 + srow) * TOKENS + scol,\
                  &Vt[1 - (CUR)][w * 1024 + 512]);                                \
      asm volatile("s_waitcnt vmcnt(4)" ::: "memory");                            \
    } else {                                                                      \
      asm volatile("s_waitcnt vmcnt(0)" ::: "memory");                            \
    }                                                                             \
    __builtin_amdgcn_s_barrier();                                                 \
    __builtin_amdgcn_sched_barrier(0);                                            \
    f32x4 sacc[4] = {};                                                           \
    __builtin_amdgcn_s_setprio(1);                                                \
    for (int nf = 0; nf < 4; ++nf) {                                              \
      short8 bk0 = *(const short8*)&Ks[CUR][koffs0[nf]];                          \
      short8 bk1 = *(const short8*)&Ks[CUR][koffs1[nf]];                          \
      sacc[nf] = __builtin_amdgcn_mfma_f32_16x16x32_bf16(bk0, aq0, sacc[nf], 0, 0, 0);\
      sacc[nf] = __builtin_amdgcn_mfma_f32_16x16x32_bf16(bk1, aq1, sacc[nf], 0, 0, 0);\
    }                                                                             \
    __builtin_amdgcn_s_setprio(0);                                                \
    float a0 = fmaxf(fmaxf(sacc[0][0], sacc[0][1]), sacc[0][2]);                  \
    float a1 = fmaxf(fmaxf(sacc[0][3], sacc[1][0]), sacc[1][1]);                  \
    float a2 = fmaxf(fmaxf(sacc[1][2], sacc[1][3]), sacc[2][0]);                  \
    float a3 = fmaxf(fmaxf(sacc[2][1], sacc[2][2]), sacc[2][3]);                  \
    float a4 = fmaxf(fmaxf(sacc[3][0], sacc[3][1]), sacc[3][2]);                  \
    float tm = fmaxf(fmaxf(fmaxf(a0, a1), fmaxf(a2, a3)), fmaxf(a4, sacc[3][3])); \
    tm *= SCL;                                                                    \
    tm = fmaxf(tm, __shfl_xor(tm, 16));                                           \
    tm = fmaxf(tm, __shfl_xor(tm, 32));                                           \
    if (__any(tm > m_run + 5.f)) {   /* defer-max: P bounded by 2^5 */            \
      const float mnew = fmaxf(m_run, tm);                                        \
      const float alpha = exp2f(m_run - mnew);                                    \
      m_run = mnew; l_run *= alpha;                                               \
      const float ar0 = __shfl(alpha, lh4 + 0), ar1 = __shfl(alpha, lh4 + 1);     \
      const float ar2 = __shfl(alpha, lh4 + 2), ar3 = __shfl(alpha, lh4 + 3);     \
      for (int nf = 0; nf < 4; ++nf) {                                            \
        oacc[nf][0] *= ar0; oacc[nf][1] *= ar1;                                   \
        oacc[nf][2] *= ar2; oacc[nf][3] *= ar3;                                   \
      }                                                                           \
    }                                                                             \
    float rs = 0.f;                                                               \
    for (int nf = 0; nf < 4; ++nf) {                                              \
      float p0 = exp2f(__builtin_fmaf(sacc[nf][0], SCL, -m_run));                 \
      float p1 = exp2f(__builtin_fmaf(sacc[nf][1], SCL, -m_run));                 \
      float p2 = exp2f(__builtin_fmaf(sacc[nf][2], SCL, -m_run));                 \
      float p3 = exp2f(__builtin_fmaf(sacc[nf][3], SCL, -m_run));                 \
      rs += (p0 + p1) + (p2 + p3);                                                \
      unsigned pk0, pk1;                                                          \
      asm("v_cvt_pk_bf16_f32 %0, %1, %2" : "=v"(pk0) : "v"(p0), "v"(p1));         \
      asm("v_cvt_pk_bf16_f32 %0, %1, %2" : "=v"(pk1) : "v"(p2), "v"(p3));         \
      uint2 pw; pw.x = pk0; pw.y = pk1;                                           \
      *(uint2*)&Ps[w][lr * 72 + nf * 16 + lh4] = pw;                              \
    }                                                                             \
    rs += __shfl_xor(rs, 16);                                                     \
    rs += __shfl_xor(rs, 32);                                                     \
    l_run += rs;                                                                  \
    short8 pa0 = *(const short8*)pa0p;                                            \
    short8 pa1 = *(const short8*)pa1p;                                            \
    __builtin_amdgcn_s_setprio(1);                                                \
    for (int nf = 0; nf < 4; ++nf) {                                              \
      short8 vb0 = *(const short8*)&Vt[CUR][voffs0[nf]];                          \
      short8 vb1 = *(const short8*)&Vt[CUR][voffs1[nf]];                          \
      oacc[nf] = __builtin_amdgcn_mfma_f32_16x16x32_bf16(pa0, vb0, oacc[nf], 0, 0, 0);\
      oacc[nf] = __builtin_amdgcn_mfma_f32_16x16x32_bf16(pa1, vb1, oacc[nf], 0, 0, 0);\
    }                                                                             \
    __builtin_amdgcn_s_setprio(0);                                                \
    __builtin_amdgcn_s_barrier();   /* WAR: all reads of buf[CUR] done */         \
    __builtin_amdgcn_sched_barrier(0);                                            \
  }

  for (int kt2 = 0; kt2 < NT; kt2 += 2) {
    ATTN_STEP(0, kt2)
    ATTN_STEP(1, kt2 + 1)
  }
#undef ATTN_STEP

  const float lf0 = __shfl(l_run, lh4 + 0);
  const float lf1 = __shfl(l_run, lh4 + 1);
  const float lf2 = __shfl(l_run, lh4 + 2);
  const float lf3 = __shfl(l_run, lh4 + 3);
  const float ri0 = 1.f / lf0, ri1 = 1.f / lf1, ri2 = 1.f / lf2, ri3 = 1.f / lf3;
  for (int nf = 0; nf < 4; ++nf) {
    const int col = h * 64 + nf * 16 + lr;
    const size_t rowb = (tokbase + q0 + w * 16 + lh4) * (size_t)CMODEL + col;
    outb[rowb]               = f2bf(oacc[nf][0] * ri0);
    outb[rowb + CMODEL]      = f2bf(oacc[nf][1] * ri1);
    outb[rowb + 2 * CMODEL]  = f2bf(oacc[nf][2] * ri2);
    outb[rowb + 3 * CMODEL]  = f2bf(oacc[nf][3] * ri3);
  }
}

// ---------------- LN1: z = p0+p1+src+b_proj; x = LN(z)*g+b -> bf16 ----------
__global__ __launch_bounds__(256) void k_ln1(
    const float* __restrict__ p,      // [2][TOKENS][CMODEL]
    const float* __restrict__ src, const float* __restrict__ bias,
    const float* __restrict__ g, const float* __restrict__ b,
    unsigned short* __restrict__ xout)
{
  const int row = blockIdx.x;
  const int t = threadIdx.x;
  const size_t rb = (size_t)row * CMODEL;
  const float4 a0 = ((const float4*)(p + rb))[t];
  const float4 a1 = ((const float4*)(p + (size_t)TOKENS * CMODEL + rb))[t];
  const float4 sv = ((const float4*)(src + rb))[t];
  const float4 bb = ((const float4*)bias)[t];
  float4 v;
  v.x = a0.x + a1.x + sv.x + bb.x;
  v.y = a0.y + a1.y + sv.y + bb.y;
  v.z = a0.z + a1.z + sv.z + bb.z;
  v.w = a0.w + a1.w + sv.w + bb.w;
  float s  = v.x + v.y + v.z + v.w;
  float s2 = v.x * v.x + v.y * v.y + v.z * v.z + v.w * v.w;
  for (int off = 32; off; off >>= 1) { s += __shfl_down(s, off); s2 += __shfl_down(s2, off); }
  __shared__ float red[8];
  __shared__ float stats[2];
  const int wv = t >> 6;
  if ((t & 63) == 0) { red[wv] = s; red[4 + wv] = s2; }
  __syncthreads();
  if (t == 0) {
    float ts  = red[0] + red[1] + red[2] + red[3];
    float ts2 = red[4] + red[5] + red[6] + red[7];
    float mu  = ts * (1.f / CMODEL);
    float var = ts2 * (1.f / CMODEL) - mu * mu;
    stats[0] = mu; stats[1] = rsqrtf(var + 1e-5f);
  }
  __syncthreads();
  const float mu = stats[0], rstd = stats[1];
  float4 gv = ((const float4*)g)[t];
  float4 bv = ((const float4*)b)[t];
  ushort4v o;
  o[0] = f2bf((v.x - mu) * rstd * gv.x + bv.x);
  o[1] = f2bf((v.y - mu) * rstd * gv.y + bv.y);
  o[2] = f2bf((v.z - mu) * rstd * gv.z + bv.z);
  o[3] = f2bf((v.w - mu) * rstd * gv.w + bv.w);
  ((ushort4v*)(xout + rb))[t] = o;
}

// ---------------- LN2: z = q0+q1+x+b2; out = LN(z)*g+b -> f32 ----------------
__global__ __launch_bounds__(256) void k_ln2(
    const float* __restrict__ q,      // [2][TOKENS][CMODEL]
    const unsigned short* __restrict__ xres, const float* __restrict__ bias,
    const float* __restrict__ g, const float* __restrict__ b,
    float* __restrict__ out)
{
  const int row = blockIdx.x;
  const int t = threadIdx.x;
  const size_t rb = (size_t)row * CMODEL;
  const float4 a0 = ((const float4*)(q + rb))[t];
  const float4 a1 = ((const float4*)(q + (size_t)TOKENS * CMODEL + rb))[t];
  const ushort4v xv = ((const ushort4v*)(xres + rb))[t];
  const float4 bb = ((const float4*)bias)[t];
  float4 v;
  v.x = a0.x + a1.x + bf2f(xv[0]) + bb.x;
  v.y = a0.y + a1.y + bf2f(xv[1]) + bb.y;
  v.z = a0.z + a1.z + bf2f(xv[2]) + bb.z;
  v.w = a0.w + a1.w + bf2f(xv[3]) + bb.w;
  float s  = v.x + v.y + v.z + v.w;
  float s2 = v.x * v.x + v.y * v.y + v.z * v.z + v.w * v.w;
  for (int off = 32; off; off >>= 1) { s += __shfl_down(s, off); s2 += __shfl_down(s2, off); }
  __shared__ float red[8];
  __shared__ float stats[2];
  const int wv = t >> 6;
  if ((t & 63) == 0) { red[wv] = s; red[4 + wv] = s2; }
  __syncthreads();
  if (t == 0) {
    float ts  = red[0] + red[1] + red[2] + red[3];
    float ts2 = red[4] + red[5] + red[6] + red[7];
    float mu  = ts * (1.f / CMODEL);
    float var = ts2 * (1.f / CMODEL) - mu * mu;
    stats[0] = mu; stats[1] = rsqrtf(var + 1e-5f);
  }
  __syncthreads();
  const float mu = stats[0], rstd = stats[1];
  float4 gv = ((const float4*)g)[t];
  float4 bv = ((const float4*)b)[t];
  float4 o;
  o.x = (v.x - mu) * rstd * gv.x + bv.x;
  o.y = (v.y - mu) * rstd * gv.y + bv.y;
  o.z = (v.z - mu) * rstd * gv.z + bv.z;
  o.w = (v.w - mu) * rstd * gv.w + bv.w;
  ((float4*)(out + rb))[t] = o;
}

// ---------------- launch ----------------
extern "C" void kernel_launch(void* const* d_in, const int* in_sizes, int n_in,
                              void* d_out, int out_size, void* d_ws, size_t ws_size,
                              hipStream_t stream) {
  const float* src    = (const float*)d_in[0];
  const float* w_qkv  = (const float*)d_in[1];
  const float* w_proj = (const float*)d_in[2];
  const float* b_proj = (const float*)d_in[3];
  const float* w1     = (const float*)d_in[4];
  const float* b1     = (const float*)d_in[5];
  const float* w2     = (const float*)d_in[6];
  const float* b2     = (const float*)d_in[7];
  const float* g1     = (const float*)d_in[8];
  const float* be1    = (const float*)d_in[9];
  const float* g2     = (const float*)d_in[10];
  const float* be2    = (const float*)d_in[11];
  float* out = (float*)d_out;

  char* ws = (char*)d_ws;
  size_t off = 0;
  auto alloc = [&](size_t bytes) -> void* {
    void* p = ws + off;
    off += (bytes + 255) & ~(size_t)255;
    return p;
  };
  unsigned short* src_bf   = (unsigned short*)alloc((size_t)TOKENS * CMODEL * 2);      // 8 MB
  unsigned short* wqkv_bf  = (unsigned short*)alloc((size_t)3 * CMODEL * CMODEL * 2);  // 6 MB
  unsigned short* wproj_bf = (unsigned short*)alloc((size_t)CMODEL * CMODEL * 2);      // 2 MB
  unsigned short* w1_bf    = (unsigned short*)alloc((size_t)DFF * CMODEL * 2);         // 8 MB
  unsigned short* w2_bf    = (unsigned short*)alloc((size_t)CMODEL * DFF * 2);         // 8 MB
  unsigned short* x_bf     = (unsigned short*)alloc((size_t)TOKENS * CMODEL * 2);      // 8 MB
  unsigned short* h_bf     = (unsigned short*)alloc((size_t)TOKENS * DFF * 2);         // 32 MB
  // region R: qk (16 MB) + vT (8 MB) + attno (8 MB) + p_proj (32 MB) = 64 MB
  // p_ffn2 (32 MB) aliases region start (qk/vT/attno/p_proj dead by then)
  char* regionR = (char*)alloc((size_t)64 * 1024 * 1024);
  unsigned short* qk_bf    = (unsigned short*)regionR;                                  // [4096][2048]
  unsigned short* vT_bf    = (unsigned short*)(regionR + (size_t)TOKENS * 2048 * 2);    // [1024][4096]
  unsigned short* attno_bf = (unsigned short*)(regionR + (size_t)TOKENS * 2048 * 2
                                                       + (size_t)CMODEL * TOKENS * 2);
  float*          p_proj   = (float*)(regionR + (size_t)TOKENS * 2048 * 2
                                              + (size_t)CMODEL * TOKENS * 2
                                              + (size_t)TOKENS * CMODEL * 2);
  float*          p_ffn2   = (float*)regionR;   // [2][TOKENS][CMODEL] f32

  // 1. convert all inputs to bf16 (single kernel)
  k_cvt_all<<<CVT_B4 / 256, 256, 0, stream>>>(src, w_qkv, w_proj, w1, w2,
      src_bf, wqkv_bf, wproj_bf, w1_bf, w2_bf);
  // 2a. qk = src @ w_qk^T           [4096, 2048]
  k_gemm_bt<0><<<dim3(2048 / 128, TOKENS / 128), 256, 0, stream>>>(
      src_bf, wqkv_bf, qk_bf, nullptr, nullptr, TOKENS, 2048, CMODEL, CMODEL);
  // 2b. vT = w_v @ src^T            [1024, 4096]  (V pre-transposed)
  k_gemm_bt<0><<<dim3(TOKENS / 128, CMODEL / 128), 256, 0, stream>>>(
      wqkv_bf + (size_t)2048 * CMODEL, src_bf, vT_bf, nullptr, nullptr,
      CMODEL, TOKENS, CMODEL, CMODEL);
  // 3. attention -> attno           [4096, 1024]
  k_attn<<<dim3(SEQ / 64, 2 * HEADS), 256, 0, stream>>>(qk_bf, vT_bf, attno_bf);
  // 4. p_proj[z] = attno @ w_proj^T (split-K2, f32 partials)
  k_gemm_bt<4><<<dim3(CMODEL / 128, TOKENS / 128, 2), 256, 0, stream>>>(
      attno_bf, wproj_bf, nullptr, p_proj, nullptr, TOKENS, CMODEL, CMODEL, CMODEL / 2);
  // 5. x = LN1(p0+p1+src+b_proj) -> bf16
  k_ln1<<<TOKENS, 256, 0, stream>>>(p_proj, src, b_proj, g1, be1, x_bf);
  // 6. h = relu(x @ w1^T + b1) -> bf16    [4096, 4096]
  k_gemm_bt<2><<<dim3(DFF / 128, TOKENS / 128), 256, 0, stream>>>(
      x_bf, w1_bf, h_bf, nullptr, b1, TOKENS, DFF, CMODEL, CMODEL);
  // 7. p_ffn2[z] = h @ w2^T (split-K2, f32 partials)
  k_gemm_bt<4><<<dim3(CMODEL / 128, TOKENS / 128, 2), 256, 0, stream>>>(
      h_bf, w2_bf, nullptr, p_ffn2, nullptr, TOKENS, CMODEL, DFF, DFF / 2);
  // 8. out = LN2(q0+q1+x+b2)
  k_ln2<<<TOKENS, 256, 0, stream>>>(p_ffn2, x_bf, b2, g2, be2, out);
}

// Round 8
// 396.059 us; speedup vs baseline: 1.0118x; 1.0118x over previous
//
#include <hip/hip_runtime.h>
#include <hip/hip_bf16.h>
#include <stdint.h>

// ---- problem constants ----
#define TOKENS 4096      // B*N = 2*2048
#define SEQ    2048
#define CMODEL 1024
#define HEADS  16
#define HDIM   64
#define DFF    4096
#define NT     (SEQ / 64)

typedef __attribute__((ext_vector_type(8))) short     short8;
typedef __attribute__((ext_vector_type(8))) unsigned short ushort8;
typedef __attribute__((ext_vector_type(4))) unsigned short ushort4v;
typedef __attribute__((ext_vector_type(4))) float     f32x4;

typedef const __attribute__((address_space(1))) void gbl_cvoid;
typedef __attribute__((address_space(3))) void lds_void;

__device__ inline unsigned short f2bf(float f) {
  unsigned int u = __builtin_bit_cast(unsigned int, f);
  u += 0x7fffu + ((u >> 16) & 1u);
  return (unsigned short)(u >> 16);
}
__device__ inline float bf2f(unsigned short h) {
  unsigned int u = ((unsigned int)h) << 16;
  return __builtin_bit_cast(float, u);
}

__device__ inline void gload_lds16(const unsigned short* g, unsigned short* lds) {
  __builtin_amdgcn_global_load_lds((gbl_cvoid*)g, (lds_void*)lds, 16, 0, 0);
}

// ---------------- fused f32 -> bf16 convert for all 5 tensors ----------------
#define CVT_B0 524288    // src      4096*1024/8
#define CVT_B1 917504    // + w_qkv  3*1024*1024/8
#define CVT_B2 1048576   // + w_proj 1024*1024/8
#define CVT_B3 1572864   // + w1     4096*1024/8
#define CVT_B4 2097152   // + w2     1024*4096/8
__global__ __launch_bounds__(256) void k_cvt_all(
    const float* __restrict__ src, const float* __restrict__ wqkv,
    const float* __restrict__ wproj, const float* __restrict__ w1,
    const float* __restrict__ w2,
    unsigned short* __restrict__ o_src, unsigned short* __restrict__ o_wqkv,
    unsigned short* __restrict__ o_wproj, unsigned short* __restrict__ o_w1,
    unsigned short* __restrict__ o_w2)
{
  const int i = blockIdx.x * 256 + threadIdx.x;
  const float* in;
  unsigned short* out;
  int off;
  if (i < CVT_B0)      { in = src;   out = o_src;   off = i; }
  else if (i < CVT_B1) { in = wqkv;  out = o_wqkv;  off = i - CVT_B0; }
  else if (i < CVT_B2) { in = wproj; out = o_wproj; off = i - CVT_B1; }
  else if (i < CVT_B3) { in = w1;    out = o_w1;    off = i - CVT_B2; }
  else                 { in = w2;    out = o_w2;    off = i - CVT_B3; }
  const float4* p = (const float4*)in + 2 * (size_t)off;
  float4 a = p[0], b = p[1];
  ushort8 o;
  o[0] = f2bf(a.x); o[1] = f2bf(a.y); o[2] = f2bf(a.z); o[3] = f2bf(a.w);
  o[4] = f2bf(b.x); o[5] = f2bf(b.y); o[6] = f2bf(b.z); o[7] = f2bf(b.w);
  ((ushort8*)out)[off] = o;
}

// ---------------- bf16 BT-GEMM 128xBN: C[M,N] = A[M,K] @ B[N,K]^T --------
// BM=128, BN in {128, 64}. BK=32, 4 waves (2x2). 3-deep LDS pipeline:
// stage(kt+2), counted vmcnt. Full K always (no split-K).
// EPI: 0 = bf16; 1 = f32 +bias+res_f32; 2 = bf16 relu(+bias); 3 = f32 +bias+res_bf16
template<int EPI, int BN>
__global__ __launch_bounds__(256) void k_gemm_bt(
    const unsigned short* __restrict__ A,
    const unsigned short* __restrict__ B,
    unsigned short* __restrict__ Cb,
    float* __restrict__ Cf,
    const float* __restrict__ bias,
    const float* __restrict__ resf,
    const unsigned short* __restrict__ resb,
    int M, int N, int K)
{
  constexpr int NF = BN >> 5;            // frags per wave in N (4 or 2)
  __shared__ unsigned short As[3][128 * 32];
  __shared__ unsigned short Bs[3][BN * 32];
  const int t = threadIdx.x;
  const int lane = t & 63;
  const int w = t >> 6;
  const int wr = w >> 1, wc = w & 1;
  const int nwg = gridDim.x * gridDim.y;
  const int bid = blockIdx.y * gridDim.x + blockIdx.x;
  const int swz = (bid & 7) * (nwg >> 3) + (bid >> 3);
  const int n0 = (swz % gridDim.x) * BN;
  const int m0 = (swz / gridDim.x) * 128;

  const int e0 = w * 1024 + lane * 8;
  const int e1 = e0 + 512;
  const int r0 = e0 >> 5, c0 = e0 & 31;
  const int r1 = e1 >> 5, c1 = e1 & 31;
  const int eB = w * 512 + lane * 8;       // BN=64 staging
  const int rB = eB >> 5, cB = eB & 31;

  f32x4 acc[4][NF] = {};
  const int lr = lane & 15, lh = lane >> 4;
  const int nkt = K >> 5;

  auto stage = [&](int kt, int buf) {
    const int kb = kt << 5;
    gload_lds16(A + (size_t)(m0 + r0) * K + kb + c0, &As[buf][w * 1024]);
    gload_lds16(A + (size_t)(m0 + r1) * K + kb + c1, &As[buf][w * 1024 + 512]);
    if constexpr (BN == 128) {
      gload_lds16(B + (size_t)(n0 + r0) * K + kb + c0, &Bs[buf][w * 1024]);
      gload_lds16(B + (size_t)(n0 + r1) * K + kb + c1, &Bs[buf][w * 1024 + 512]);
    } else {
      gload_lds16(B + (size_t)(n0 + rB) * K + kb + cB, &Bs[buf][w * 512]);
    }
  };
  stage(0, 0);
  if (nkt > 1) stage(1, 1);

  int buf = 0;
  for (int kt = 0; kt < nkt; ++kt) {
    if (kt + 2 < nkt) {
      const int nb = buf + 2 >= 3 ? buf - 1 : buf + 2;
      stage(kt + 2, nb);
      if constexpr (BN == 128) asm volatile("s_waitcnt vmcnt(8)" ::: "memory");
      else                     asm volatile("s_waitcnt vmcnt(6)" ::: "memory");
    } else if (kt + 1 < nkt) {
      if constexpr (BN == 128) asm volatile("s_waitcnt vmcnt(4)" ::: "memory");
      else                     asm volatile("s_waitcnt vmcnt(3)" ::: "memory");
    } else {
      asm volatile("s_waitcnt vmcnt(0)" ::: "memory");
    }
    __builtin_amdgcn_s_barrier();
    __builtin_amdgcn_sched_barrier(0);
    short8 af[4], bg[NF];
#pragma unroll
    for (int m = 0; m < 4; ++m)
      af[m] = *(const short8*)&As[buf][(wr * 64 + m * 16 + lr) * 32 + lh * 8];
#pragma unroll
    for (int n = 0; n < NF; ++n)
      bg[n] = *(const short8*)&Bs[buf][(wc * (BN / 2) + n * 16 + lr) * 32 + lh * 8];
#pragma unroll
    for (int m = 0; m < 4; ++m)
#pragma unroll
      for (int n = 0; n < NF; ++n)
        acc[m][n] = __builtin_amdgcn_mfma_f32_16x16x32_bf16(af[m], bg[n], acc[m][n], 0, 0, 0);
    __builtin_amdgcn_s_barrier();
    __builtin_amdgcn_sched_barrier(0);
    buf = buf + 1 >= 3 ? 0 : buf + 1;
  }

  for (int m = 0; m < 4; ++m) {
    for (int n = 0; n < NF; ++n) {
      const int col = n0 + wc * (BN / 2) + n * 16 + lr;
      for (int r = 0; r < 4; ++r) {
        const int row = m0 + wr * 64 + m * 16 + lh * 4 + r;
        const size_t idx = (size_t)row * N + col;
        float v = acc[m][n][r];
        if (EPI == 0) {
          Cb[idx] = f2bf(v);
        } else if (EPI == 1) {
          Cf[idx] = v + bias[col] + resf[idx];
        } else if (EPI == 2) {
          v += bias[col];
          Cb[idx] = f2bf(v > 0.f ? v : 0.f);
        } else {  // EPI == 3
          Cf[idx] = v + bias[col] + bf2f(resb[idx]);
        }
      }
    }
  }
}

// ---------------- flash attention: QBLK=64, KVBLK=64, 4 waves ----------------
// Q/K from qk[token][2048]; V pre-transposed vT[h*64+d][token]. Both staged via
// global_load_lds (pre-swizzled source, XOR-swizzled reads). LDS 40 KB:
// QPs union (Q strip dead after prologue register read -> reused as P strip,
// XOR chunk swizzle instead of padding).
__global__ __launch_bounds__(256) void k_attn(
    const unsigned short* __restrict__ qk,   // [token][2048]
    const unsigned short* __restrict__ vT,   // [1024][TOKENS]
    unsigned short* __restrict__ outb)       // [token][1024]
{
  __shared__ unsigned short Ks[2][64 * 64];
  __shared__ unsigned short Vt[2][64 * 64];
  __shared__ unsigned short QPs[4 * 1024];   // per-wave 1024 shorts: Q then P

  const int t = threadIdx.x, lane = t & 63, w = t >> 6;
  const int bid0 = blockIdx.y * 32 + blockIdx.x;
  const int swz = (bid0 & 7) * 128 + (bid0 >> 3);
  const int bh = swz >> 5;
  const int b = bh >> 4, h = bh & 15;
  const int q0 = (swz & 31) * 64;
  const size_t tokbase = (size_t)b * SEQ;
  const int qoff = h * 64, koff = 1024 + h * 64;
  const size_t vbase = (size_t)(h * 64) * TOKENS + tokbase;
  const int lr = lane & 15, lh = lane >> 4, lh4 = lh * 4;

  const int srow = lane >> 3;
  const int scol = (((lane & 7) ^ srow) & 7) << 3;

  // prologue: Q, K0, V0
  gload_lds16(qk + (tokbase + q0 + w * 16 + srow) * 2048 + qoff + scol, &QPs[w * 1024]);
  gload_lds16(qk + (tokbase + q0 + w * 16 + 8 + srow) * 2048 + qoff + scol, &QPs[w * 1024 + 512]);
  gload_lds16(qk + (tokbase + w * 16 + srow) * 2048 + koff + scol, &Ks[0][w * 1024]);
  gload_lds16(qk + (tokbase + w * 16 + 8 + srow) * 2048 + koff + scol, &Ks[0][w * 1024 + 512]);
  gload_lds16(vT + vbase + (size_t)(w * 16 + srow) * TOKENS + scol, &Vt[0][w * 1024]);
  gload_lds16(vT + vbase + (size_t)(w * 16 + 8 + srow) * TOKENS + scol, &Vt[0][w * 1024 + 512]);
  asm volatile("s_waitcnt vmcnt(0)" ::: "memory");
  __builtin_amdgcn_s_barrier();
  __builtin_amdgcn_sched_barrier(0);

  // Q fragments (B-operand of swapped QK^T); QPs strip is per-wave private,
  // dead after these two reads -> reused as the P strip below.
  const short8 aq0 = *(const short8*)&QPs[w * 1024 + lr * 64 + (((lh ^ (lr & 7)) & 7) << 3)];
  const short8 aq1 = *(const short8*)&QPs[w * 1024 + lr * 64 + ((((lh + 4) ^ (lr & 7)) & 7) << 3)];

  int koffs0[4], koffs1[4];
  for (int nf = 0; nf < 4; ++nf) {
    const int krow = nf * 16 + lr;
    koffs0[nf] = krow * 64 + (((lh ^ (lr & 7)) & 7) << 3);
    koffs1[nf] = krow * 64 + ((((lh + 4) ^ (lr & 7)) & 7) << 3);
  }
  // P strip read pointers (chunk-swizzled, pitch 64)
  const unsigned short* pa0p = &QPs[w * 1024 + lr * 64 + (((lh ^ (lr & 7)) & 7) << 3)];
  const unsigned short* pa1p = &QPs[w * 1024 + lr * 64 + ((((4 + lh) ^ (lr & 7)) & 7) << 3)];
  // P write slots: for nf, chunk = nf*2 + (lh4>>3), swizzled by lr&7
  int pwr[4];
  for (int nf = 0; nf < 4; ++nf)
    pwr[nf] = w * 1024 + lr * 64 + ((((nf * 2 + (lh4 >> 3)) ^ (lr & 7)) & 7) << 3) + (lh4 & 7);

  float m_run = -1e30f, l_run = 0.f;
  f32x4 oacc[4] = {};
  const float SCL = 0.125f * 1.44269504089f;  // head_scale * log2(e)

#define ATTN_STEP(CUR, KT)                                                        \
  {                                                                               \
    const int ktn = (KT) + 1;                                                     \
    if (ktn < NT) {                                                               \
      gload_lds16(qk + (tokbase + ktn * 64 + w * 16 + srow) * 2048 + koff + scol, \
                  &Ks[1 - (CUR)][w * 1024]);                                      \
      gload_lds16(qk + (tokbase + ktn * 64 + w * 16 + 8 + srow) * 2048 + koff + scol,\
                  &Ks[1 - (CUR)][w * 1024 + 512]);                                \
      gload_lds16(vT + vbase + ktn * 64 + (size_t)(w * 16 + srow) * TOKENS + scol,\
                  &Vt[1 - (CUR)][w * 1024]);                                      \
      gload_lds16(vT + vbase + ktn * 64 + (size_t)(w * 16 + 8 + srow) * TOKENS + scol,\
                  &Vt[1 - (CUR)][w * 1024 + 512]);                                \
      asm volatile("s_waitcnt vmcnt(4)" ::: "memory");                            \
    } else {                                                                      \
      asm volatile("s_waitcnt vmcnt(0)" ::: "memory");                            \
    }                                                                             \
    __builtin_amdgcn_s_barrier();                                                 \
    __builtin_amdgcn_sched_barrier(0);                                            \
    f32x4 sacc[4] = {};                                                           \
    __builtin_amdgcn_s_setprio(1);                                                \
    for (int nf = 0; nf < 4; ++nf) {                                              \
      short8 bk0 = *(const short8*)&Ks[CUR][koffs0[nf]];                          \
      short8 bk1 = *(const short8*)&Ks[CUR][koffs1[nf]];                          \
      sacc[nf] = __builtin_amdgcn_mfma_f32_16x16x32_bf16(bk0, aq0, sacc[nf], 0, 0, 0);\
      sacc[nf] = __builtin_amdgcn_mfma_f32_16x16x32_bf16(bk1, aq1, sacc[nf], 0, 0, 0);\
    }                                                                             \
    __builtin_amdgcn_s_setprio(0);                                                \
    float a0 = fmaxf(fmaxf(sacc[0][0], sacc[0][1]), sacc[0][2]);                  \
    float a1 = fmaxf(fmaxf(sacc[0][3], sacc[1][0]), sacc[1][1]);                  \
    float a2 = fmaxf(fmaxf(sacc[1][2], sacc[1][3]), sacc[2][0]);                  \
    float a3 = fmaxf(fmaxf(sacc[2][1], sacc[2][2]), sacc[2][3]);                  \
    float a4 = fmaxf(fmaxf(sacc[3][0], sacc[3][1]), sacc[3][2]);                  \
    float tm = fmaxf(fmaxf(fmaxf(a0, a1), fmaxf(a2, a3)), fmaxf(a4, sacc[3][3])); \
    tm *= SCL;                                                                    \
    tm = fmaxf(tm, __shfl_xor(tm, 16));                                           \
    tm = fmaxf(tm, __shfl_xor(tm, 32));                                           \
    if (__any(tm > m_run + 5.f)) {   /* defer-max: P bounded by 2^5 */            \
      const float mnew = fmaxf(m_run, tm);                                        \
      const float alpha = exp2f(m_run - mnew);                                    \
      m_run = mnew; l_run *= alpha;                                               \
      const float ar0 = __shfl(alpha, lh4 + 0), ar1 = __shfl(alpha, lh4 + 1);     \
      const float ar2 = __shfl(alpha, lh4 + 2), ar3 = __shfl(alpha, lh4 + 3);     \
      for (int nf = 0; nf < 4; ++nf) {                                            \
        oacc[nf][0] *= ar0; oacc[nf][1] *= ar1;                                   \
        oacc[nf][2] *= ar2; oacc[nf][3] *= ar3;                                   \
      }                                                                           \
    }                                                                             \
    float rs = 0.f;                                                               \
    for (int nf = 0; nf < 4; ++nf) {                                              \
      float p0 = exp2f(__builtin_fmaf(sacc[nf][0], SCL, -m_run));                 \
      float p1 = exp2f(__builtin_fmaf(sacc[nf][1], SCL, -m_run));                 \
      float p2 = exp2f(__builtin_fmaf(sacc[nf][2], SCL, -m_run));                 \
      float p3 = exp2f(__builtin_fmaf(sacc[nf][3], SCL, -m_run));                 \
      rs += (p0 + p1) + (p2 + p3);                                                \
      unsigned pk0, pk1;                                                          \
      asm("v_cvt_pk_bf16_f32 %0, %1, %2" : "=v"(pk0) : "v"(p0), "v"(p1));         \
      asm("v_cvt_pk_bf16_f32 %0, %1, %2" : "=v"(pk1) : "v"(p2), "v"(p3));         \
      uint2 pw; pw.x = pk0; pw.y = pk1;                                           \
      *(uint2*)&QPs[pwr[nf]] = pw;                                                \
    }                                                                             \
    rs += __shfl_xor(rs, 16);                                                     \
    rs += __shfl_xor(rs, 32);                                                     \
    l_run += rs;                                                                  \
    short8 pa0 = *(const short8*)pa0p;                                            \
    short8 pa1 = *(const short8*)pa1p;                                            \
    __builtin_amdgcn_s_setprio(1);                                                \
    for (int nf = 0; nf < 4; ++nf) {                                              \
      short8 vb0 = *(const short8*)&Vt[CUR][koffs0[nf]];                          \
      short8 vb1 = *(const short8*)&Vt[CUR][koffs1[nf]];                          \
      oacc[nf] = __builtin_amdgcn_mfma_f32_16x16x32_bf16(pa0, vb0, oacc[nf], 0, 0, 0);\
      oacc[nf] = __builtin_amdgcn_mfma_f32_16x16x32_bf16(pa1, vb1, oacc[nf], 0, 0, 0);\
    }                                                                             \
    __builtin_amdgcn_s_setprio(0);                                                \
    __builtin_amdgcn_s_barrier();   /* WAR: all reads of buf[CUR] done */         \
    __builtin_amdgcn_sched_barrier(0);                                            \
  }

  for (int kt2 = 0; kt2 < NT; kt2 += 2) {
    ATTN_STEP(0, kt2)
    ATTN_STEP(1, kt2 + 1)
  }
#undef ATTN_STEP

  const float lf0 = __shfl(l_run, lh4 + 0);
  const float lf1 = __shfl(l_run, lh4 + 1);
  const float lf2 = __shfl(l_run, lh4 + 2);
  const float lf3 = __shfl(l_run, lh4 + 3);
  const float ri0 = 1.f / lf0, ri1 = 1.f / lf1, ri2 = 1.f / lf2, ri3 = 1.f / lf3;
  for (int nf = 0; nf < 4; ++nf) {
    const int col = h * 64 + nf * 16 + lr;
    const size_t rowb = (tokbase + q0 + w * 16 + lh4) * (size_t)CMODEL + col;
    outb[rowb]               = f2bf(oacc[nf][0] * ri0);
    outb[rowb + CMODEL]      = f2bf(oacc[nf][1] * ri1);
    outb[rowb + 2 * CMODEL]  = f2bf(oacc[nf][2] * ri2);
    outb[rowb + 3 * CMODEL]  = f2bf(oacc[nf][3] * ri3);
  }
}

// ---------------- LayerNorm over rows of 1024 ----------------
template<int OUT_BF>
__global__ __launch_bounds__(256) void k_ln(const float* __restrict__ in,
    const float* __restrict__ g, const float* __restrict__ b,
    float* __restrict__ outf, unsigned short* __restrict__ outb)
{
  const int row = blockIdx.x;
  const int t = threadIdx.x;
  const float4* x4 = (const float4*)(in + (size_t)row * CMODEL);
  float4 v = x4[t];
  float s  = v.x + v.y + v.z + v.w;
  float s2 = v.x * v.x + v.y * v.y + v.z * v.z + v.w * v.w;
  for (int off = 32; off; off >>= 1) { s += __shfl_down(s, off); s2 += __shfl_down(s2, off); }
  __shared__ float red[8];
  __shared__ float stats[2];
  const int wv = t >> 6;
  if ((t & 63) == 0) { red[wv] = s; red[4 + wv] = s2; }
  __syncthreads();
  if (t == 0) {
    float ts  = red[0] + red[1] + red[2] + red[3];
    float ts2 = red[4] + red[5] + red[6] + red[7];
    float mu  = ts * (1.f / CMODEL);
    float var = ts2 * (1.f / CMODEL) - mu * mu;
    stats[0] = mu; stats[1] = rsqrtf(var + 1e-5f);
  }
  __syncthreads();
  const float mu = stats[0], rstd = stats[1];
  float4 gv = ((const float4*)g)[t];
  float4 bv = ((const float4*)b)[t];
  float o0 = (v.x - mu) * rstd * gv.x + bv.x;
  float o1 = (v.y - mu) * rstd * gv.y + bv.y;
  float o2 = (v.z - mu) * rstd * gv.z + bv.z;
  float o3 = (v.w - mu) * rstd * gv.w + bv.w;
  if (OUT_BF) {
    ushort4v o; o[0] = f2bf(o0); o[1] = f2bf(o1); o[2] = f2bf(o2); o[3] = f2bf(o3);
    ((ushort4v*)(outb + (size_t)row * CMODEL))[t] = o;
  } else {
    float4 o; o.x = o0; o.y = o1; o.z = o2; o.w = o3;
    ((float4*)(outf + (size_t)row * CMODEL))[t] = o;
  }
}

// ---------------- launch ----------------
extern "C" void kernel_launch(void* const* d_in, const int* in_sizes, int n_in,
                              void* d_out, int out_size, void* d_ws, size_t ws_size,
                              hipStream_t stream) {
  const float* src    = (const float*)d_in[0];
  const float* w_qkv  = (const float*)d_in[1];
  const float* w_proj = (const float*)d_in[2];
  const float* b_proj = (const float*)d_in[3];
  const float* w1     = (const float*)d_in[4];
  const float* b1     = (const float*)d_in[5];
  const float* w2     = (const float*)d_in[6];
  const float* b2     = (const float*)d_in[7];
  const float* g1     = (const float*)d_in[8];
  const float* be1    = (const float*)d_in[9];
  const float* g2     = (const float*)d_in[10];
  const float* be2    = (const float*)d_in[11];
  float* out = (float*)d_out;

  char* ws = (char*)d_ws;
  size_t off = 0;
  auto alloc = [&](size_t bytes) -> void* {
    void* p = ws + off;
    off += (bytes + 255) & ~(size_t)255;
    return p;
  };
  unsigned short* src_bf   = (unsigned short*)alloc((size_t)TOKENS * CMODEL * 2);      // 8 MB
  unsigned short* wqkv_bf  = (unsigned short*)alloc((size_t)3 * CMODEL * CMODEL * 2);  // 6 MB
  unsigned short* wproj_bf = (unsigned short*)alloc((size_t)CMODEL * CMODEL * 2);      // 2 MB
  unsigned short* w1_bf    = (unsigned short*)alloc((size_t)DFF * CMODEL * 2);         // 8 MB
  unsigned short* w2_bf    = (unsigned short*)alloc((size_t)CMODEL * DFF * 2);         // 8 MB
  unsigned short* x_bf     = (unsigned short*)alloc((size_t)TOKENS * CMODEL * 2);      // 8 MB
  unsigned short* h_bf     = (unsigned short*)alloc((size_t)TOKENS * DFF * 2);         // 32 MB
  unsigned short* qk_bf    = (unsigned short*)alloc((size_t)TOKENS * 2048 * 2);        // 16 MB
  unsigned short* vT_bf    = (unsigned short*)alloc((size_t)CMODEL * TOKENS * 2);      // 8 MB
  unsigned short* attno_bf = (unsigned short*)alloc((size_t)TOKENS * CMODEL * 2);      // 8 MB
  float*          z_f32    = (float*)alloc((size_t)TOKENS * CMODEL * 4);               // 16 MB

  // 1. convert all inputs to bf16 (single kernel)
  k_cvt_all<<<CVT_B4 / 256, 256, 0, stream>>>(src, w_qkv, w_proj, w1, w2,
      src_bf, wqkv_bf, wproj_bf, w1_bf, w2_bf);
  // 2a. qk = src @ w_qk^T           [4096, 2048]
  k_gemm_bt<0, 128><<<dim3(2048 / 128, TOKENS / 128), 256, 0, stream>>>(
      src_bf, wqkv_bf, qk_bf, nullptr, nullptr, nullptr, nullptr, TOKENS, 2048, CMODEL);
  // 2b. vT = w_v @ src^T            [1024, 4096]  (V pre-transposed)
  k_gemm_bt<0, 128><<<dim3(TOKENS / 128, CMODEL / 128), 256, 0, stream>>>(
      wqkv_bf + (size_t)2048 * CMODEL, src_bf, vT_bf, nullptr, nullptr, nullptr, nullptr,
      CMODEL, TOKENS, CMODEL);
  // 3. attention -> attno           [4096, 1024]
  k_attn<<<dim3(SEQ / 64, 2 * HEADS), 256, 0, stream>>>(qk_bf, vT_bf, attno_bf);
  // 4. z = attno @ w_proj^T + b_proj + src   (f32, BN=64 full-K)
  k_gemm_bt<1, 64><<<dim3(CMODEL / 64, TOKENS / 128), 256, 0, stream>>>(
      attno_bf, wproj_bf, nullptr, z_f32, b_proj, src, nullptr, TOKENS, CMODEL, CMODEL);
  // 5. x = LN1(z) -> bf16
  k_ln<1><<<TOKENS, 256, 0, stream>>>(z_f32, g1, be1, nullptr, x_bf);
  // 6. h = relu(x @ w1^T + b1) -> bf16    [4096, 4096]
  k_gemm_bt<2, 128><<<dim3(DFF / 128, TOKENS / 128), 256, 0, stream>>>(
      x_bf, w1_bf, h_bf, nullptr, b1, nullptr, nullptr, TOKENS, DFF, CMODEL);
  // 7. z = h @ w2^T + b2 + x   (f32, BN=64 full-K, 128-iter loop)
  k_gemm_bt<3, 64><<<dim3(CMODEL / 64, TOKENS / 128), 256, 0, stream>>>(
      h_bf, w2_bf, nullptr, z_f32, b2, nullptr, x_bf, TOKENS, CMODEL, DFF);
  // 8. out = LN2(z)
  k_ln<0><<<TOKENS, 256, 0, stream>>>(z_f32, g2, be2, out, nullptr);
}